// Round 4
// baseline (136.716 us; speedup 1.0000x reference)
//
#include <hip/hip_runtime.h>
#include <hip/hip_fp16.h>
#include <math.h>
#include <stdint.h>
#include <stddef.h>

#define NLEVELS 16
#define HSIZE   32768
#define LOGH    15
#define RANKK   4
#define PRIME1  2654435761u
#define PRIME2  805459861u

#define BLK   1024
#define PPB   16384              // points per (pair,chunk) block
#define UN    4                  // points per macro-iteration (gather ILP = 32)
#define ITERS (PPB / (UN * BLK)) // 4 macro-iterations per phase

struct ResArr { float v[NLEVELS]; };

// fma with f16 operand promoted exactly to f32: acc += f16(lo/hi of pk) * w
// v_fma_mix_f32 D,S0,S1,S2 = S0*S1+S2 ; op_sel_hi[i]=1 -> Si is f16, op_sel[i] picks half
__device__ __forceinline__ void fma_mix_lo(float& acc, uint32_t pk, float w) {
    asm("v_fma_mix_f32 %0, %1, %2, %0 op_sel:[0,0,0] op_sel_hi:[1,0,0]"
        : "+v"(acc) : "v"(pk), "v"(w));
}
__device__ __forceinline__ void fma_mix_hi(float& acc, uint32_t pk, float w) {
    asm("v_fma_mix_f32 %0, %1, %2, %0 op_sel:[1,0,0] op_sel_hi:[1,0,0]"
        : "+v"(acc) : "v"(pk), "v"(w));
}

// ---------------- Kernel 1: materialize LoRA tables as packed fp16x2 ----------------
__global__ void build_tables_k(const float* __restrict__ A, const float* __restrict__ B,
                               uint32_t* __restrict__ T) {
    int i = blockIdx.x * blockDim.x + threadIdx.x;
    if (i >= NLEVELS * HSIZE) return;
    int l = i >> LOGH;
    const float4 a = *reinterpret_cast<const float4*>(A + (size_t)i * RANKK);
    const float* b = B + l * (RANKK * 2);   // [r][f]
    float f0 = a.x * b[0] + a.y * b[2] + a.z * b[4] + a.w * b[6];
    float f1 = a.x * b[1] + a.y * b[3] + a.z * b[5] + a.w * b[7];
    __half2 h = __floats2half2_rn(f0, f1);
    T[i] = *reinterpret_cast<uint32_t*>(&h);
}

// ---------------- Kernel 2: pair-of-levels encode, register-held phase-0 ----------
// grid.x = nChunks*8 ; chunk = bid % nChunks, pair = bid / nChunks (levels 2p,2p+1).
// Phase 0: stage table[2p], compute 16 pts/thread into regs (no stores).
// Phase 1: stage table[2p+1], compute, combine, store ONE float4 per point.
// 4 points per macro-iter -> 32 independent LDS gathers in flight; v_fma_mix_f32
// consumes the fp16 table entries directly (no v_cvt_f32_f16 pair per gather).
__global__ __launch_bounds__(BLK) __attribute__((amdgpu_waves_per_eu(4, 4)))
void encode_pair_k(const float* __restrict__ x, const uint32_t* __restrict__ T,
                   float* __restrict__ out, int nPoints, int nChunks, ResArr res) {
    __shared__ uint32_t lds[HSIZE];          // 128 KiB -> 1 block/CU (4 waves/EU)
    const int chunk = blockIdx.x % nChunks;
    const int pair  = blockIdx.x / nChunks;  // 0..7
    const int t     = threadIdx.x;
    const int base  = chunk * PPB;

    float2 r0[UN * ITERS];                   // phase-0 results, static-indexed only

#pragma unroll 1
    for (int phase = 0; phase < 2; ++phase) {
        const int l = 2 * pair + phase;
        // stage the level table into LDS, 16 B per lane per iter (8 iters)
        {
            const uint4* Tl4 = reinterpret_cast<const uint4*>(T + (size_t)l * HSIZE);
            uint4* lds4 = reinterpret_cast<uint4*>(lds);
#pragma unroll
            for (int k = 0; k < HSIZE / 4 / BLK; ++k)
                lds4[k * BLK + t] = Tl4[k * BLK + t];
        }
        __syncthreads();

        const float r = res.v[l];

#pragma unroll
        for (int it = 0; it < ITERS; ++it) {
            int   n[UN];
            bool  ok[UN];
            float acc0[UN], acc1[UN];
            float w2v[UN], w2a_[UN];
            float wxy00[UN], wxy10[UN], wxy01[UN], wxy11[UN];
            uint32_t hx0[UN], hx1[UN], hy0[UN], hy1[UN], hz0[UN], hz1[UN];

#pragma unroll
            for (int u = 0; u < UN; ++u) {
                n[u]  = base + it * (UN * BLK) + u * BLK + t;
                ok[u] = (n[u] < nPoints);
                int m = ok[u] ? n[u] : 0;
                // bit-exact replication of reference fp32 grid math
                float xn0 = (x[3 * m + 0] + 1.0f) * 0.5f;
                float xn1 = (x[3 * m + 1] + 1.0f) * 0.5f;
                float xn2 = (x[3 * m + 2] + 1.0f) * 0.5f;
                float xl0 = xn0 * r, xl1 = xn1 * r, xl2 = xn2 * r;
                float fl0 = floorf(xl0), fl1 = floorf(xl1), fl2 = floorf(xl2);
                float w0 = xl0 - fl0, w1 = xl1 - fl1, w2 = xl2 - fl2;
                uint32_t i0 = (uint32_t)fl0, i1 = (uint32_t)fl1, i2 = (uint32_t)fl2;

                hx0[u] = i0;          hx1[u] = i0 + 1u;
                hy0[u] = i1 * PRIME1; hy1[u] = hy0[u] + PRIME1;   // (i1+1)*P1 mod 2^32
                hz0[u] = i2 * PRIME2; hz1[u] = hz0[u] + PRIME2;

                float w0a = 1.0f - w0, w1a = 1.0f - w1;
                w2v[u] = w2; w2a_[u] = 1.0f - w2;
                wxy00[u] = w0a * w1a; wxy10[u] = w0 * w1a;
                wxy01[u] = w0a * w1;  wxy11[u] = w0 * w1;
                acc0[u] = 0.0f; acc1[u] = 0.0f;
            }

            // 32 independent gathers (8 per point, 4 points) — compiler interleaves
#pragma unroll
            for (int c = 0; c < 8; ++c) {
#pragma unroll
                for (int u = 0; u < UN; ++u) {
                    uint32_t h = ((c & 1) ? hx1[u] : hx0[u]) ^ ((c & 2) ? hy1[u] : hy0[u])
                               ^ ((c & 4) ? hz1[u] : hz0[u]);
                    uint32_t pk = lds[h & (HSIZE - 1)];
                    float wxy = (c & 2) ? ((c & 1) ? wxy11[u] : wxy01[u])
                                        : ((c & 1) ? wxy10[u] : wxy00[u]);
                    float wc = wxy * ((c & 4) ? w2v[u] : w2a_[u]);
                    fma_mix_lo(acc0[u], pk, wc);
                    fma_mix_hi(acc1[u], pk, wc);
                }
            }

#pragma unroll
            for (int u = 0; u < UN; ++u) {
                if (phase == 0) {
                    r0[UN * it + u] = make_float2(acc0[u], acc1[u]);
                } else if (ok[u]) {
                    float2 p0 = r0[UN * it + u];
                    float4 v = make_float4(p0.x, p0.y, acc0[u], acc1[u]);
                    *reinterpret_cast<float4*>(out + (size_t)n[u] * 32 + 4 * pair) = v;
                }
            }
        }
        __syncthreads();   // all waves done reading LDS before next phase restages
    }
}

// ---------------- Fallback: on-the-fly LoRA dequant, global gather (tiny ws) --------
__global__ void encode_fallback_k(const float* __restrict__ x, const float* __restrict__ A,
                                  const float* __restrict__ B, float* __restrict__ out,
                                  int nPoints, ResArr res) {
    int n = blockIdx.x * blockDim.x + threadIdx.x;
    if (n >= nPoints) return;
    float xn0 = (x[3 * n + 0] + 1.0f) * 0.5f;
    float xn1 = (x[3 * n + 1] + 1.0f) * 0.5f;
    float xn2 = (x[3 * n + 2] + 1.0f) * 0.5f;
    for (int l = 0; l < NLEVELS; ++l) {
        float r = res.v[l];
        float xl0 = xn0 * r, xl1 = xn1 * r, xl2 = xn2 * r;
        float fl0 = floorf(xl0), fl1 = floorf(xl1), fl2 = floorf(xl2);
        float w0 = xl0 - fl0, w1 = xl1 - fl1, w2 = xl2 - fl2;
        uint32_t i0 = (uint32_t)fl0, i1 = (uint32_t)fl1, i2 = (uint32_t)fl2;
        uint32_t hx0 = i0,          hx1 = i0 + 1u;
        uint32_t hy0 = i1 * PRIME1, hy1 = hy0 + PRIME1;
        uint32_t hz0 = i2 * PRIME2, hz1 = hz0 + PRIME2;
        float w0a = 1.0f - w0, w1a = 1.0f - w1, w2a = 1.0f - w2;
        float wxy00 = w0a * w1a, wxy10 = w0 * w1a, wxy01 = w0a * w1, wxy11 = w0 * w1;
        const float* b = B + l * 8;
        float b00 = b[0], b01 = b[1], b10 = b[2], b11 = b[3];
        float b20 = b[4], b21 = b[5], b30 = b[6], b31 = b[7];
        float acc0 = 0.0f, acc1 = 0.0f;
#pragma unroll
        for (int c = 0; c < 8; ++c) {
            uint32_t h = ((c & 1) ? hx1 : hx0) ^ ((c & 2) ? hy1 : hy0) ^ ((c & 4) ? hz1 : hz0);
            uint32_t idx = h & (HSIZE - 1);
            float4 a = *reinterpret_cast<const float4*>(A + ((size_t)l * HSIZE + idx) * RANKK);
            float fe0 = a.x * b00 + a.y * b10 + a.z * b20 + a.w * b30;
            float fe1 = a.x * b01 + a.y * b11 + a.z * b21 + a.w * b31;
            float wxy = (c & 2) ? ((c & 1) ? wxy11 : wxy01) : ((c & 1) ? wxy10 : wxy00);
            float wc = wxy * ((c & 4) ? w2 : w2a);
            acc0 = fmaf(fe0, wc, acc0);
            acc1 = fmaf(fe1, wc, acc1);
        }
        out[(size_t)n * 32 + 2 * l + 0] = acc0;
        out[(size_t)n * 32 + 2 * l + 1] = acc1;
    }
}

extern "C" void kernel_launch(void* const* d_in, const int* in_sizes, int n_in,
                              void* d_out, int out_size, void* d_ws, size_t ws_size,
                              hipStream_t stream) {
    const float* x = (const float*)d_in[0];
    const float* A = (const float*)d_in[1];
    const float* B = (const float*)d_in[2];
    float* out = (float*)d_out;
    int nPoints = in_sizes[0] / 3;

    // numpy's resolution ladder, bit-exact via host double libm:
    // b = exp((log(512)-log(16))/15); res_l = float32(floor(16 * b**l))
    ResArr ra;
    {
        double b = exp((log(512.0) - log(16.0)) / 15.0);
        for (int l = 0; l < NLEVELS; ++l)
            ra.v[l] = (float)floor(16.0 * pow(b, (double)l));
    }

    const size_t tblBytes = (size_t)NLEVELS * HSIZE * sizeof(uint32_t);   // 2 MiB

    if (ws_size >= tblBytes) {
        uint32_t* T = (uint32_t*)d_ws;
        int nb1 = (NLEVELS * HSIZE + 255) / 256;
        build_tables_k<<<nb1, 256, 0, stream>>>(A, B, T);
        int chunks = (nPoints + PPB - 1) / PPB;           // 32 for N=524288 (mult of 8)
        encode_pair_k<<<chunks * (NLEVELS / 2), BLK, 0, stream>>>(x, T, out, nPoints, chunks, ra);
    } else {
        encode_fallback_k<<<(nPoints + 255) / 256, 256, 0, stream>>>(x, A, B, out, nPoints, ra);
    }
}

// Round 5
// 128.918 us; speedup vs baseline: 1.0605x; 1.0605x over previous
//
#include <hip/hip_runtime.h>
#include <hip/hip_fp16.h>
#include <math.h>
#include <stdint.h>
#include <stddef.h>

#define NLEVELS 16
#define HSIZE   32768
#define LOGH    15
#define RANKK   4
#define PRIME1  2654435761u
#define PRIME2  805459861u

#define BLK  1024
#define PPB  16384               // points per (level,chunk) block -> 512 blocks @ N=524288
#define UN   2                   // 16-deep gather batch == max lgkmcnt(15) pipeline depth

struct ResArr { float v[NLEVELS]; };

// fma with f16 operand promoted exactly to f32: acc += f16(lo/hi of pk) * w
// Bit-exact vs cvt_f32_f16 + fma (verified on HW, absmax unchanged).
__device__ __forceinline__ void fma_mix_lo(float& acc, uint32_t pk, float w) {
    asm("v_fma_mix_f32 %0, %1, %2, %0 op_sel:[0,0,0] op_sel_hi:[1,0,0]"
        : "+v"(acc) : "v"(pk), "v"(w));
}
__device__ __forceinline__ void fma_mix_hi(float& acc, uint32_t pk, float w) {
    asm("v_fma_mix_f32 %0, %1, %2, %0 op_sel:[1,0,0] op_sel_hi:[1,0,0]"
        : "+v"(acc) : "v"(pk), "v"(w));
}

// ---------------- Kernel 1: materialize LoRA tables as packed fp16x2 ----------------
__global__ void build_tables_k(const float* __restrict__ A, const float* __restrict__ B,
                               uint32_t* __restrict__ T) {
    int i = blockIdx.x * blockDim.x + threadIdx.x;
    if (i >= NLEVELS * HSIZE) return;
    int l = i >> LOGH;
    const float4 a = *reinterpret_cast<const float4*>(A + (size_t)i * RANKK);
    const float* b = B + l * (RANKK * 2);   // [r][f]
    float f0 = a.x * b[0] + a.y * b[2] + a.z * b[4] + a.w * b[6];
    float f1 = a.x * b[1] + a.y * b[3] + a.z * b[5] + a.w * b[7];
    __half2 h = __floats2half2_rn(f0, f1);
    T[i] = *reinterpret_cast<uint32_t*>(&h);
}

// ---------------- Kernel 2: per-(level,chunk) encode, LDS-resident table -----------
// grid.x = nChunks*16 ; chunk = bid % nChunks (mult of 8), level = bid / nChunks.
// All 16 level-blocks of a chunk land on one XCD (round-robin bid%8) so the strided
// float2 stores combine into full lines in that XCD's L2.
// FULL=true: nPoints % PPB == 0 -> no bounds checks, unconditional stores.
template<bool FULL>
__global__ __launch_bounds__(BLK) __attribute__((amdgpu_waves_per_eu(4, 4)))
void encode_level_k(const float* __restrict__ x, const uint32_t* __restrict__ T,
                    float* __restrict__ out, int nPoints, int nChunks, ResArr res) {
    __shared__ uint32_t lds[HSIZE];          // 128 KiB -> 1 block/CU (4 waves/EU)
    const int chunk = blockIdx.x % nChunks;
    const int l     = blockIdx.x / nChunks;
    const int t     = threadIdx.x;

    // stage the whole level table into LDS, 16 B per lane per iter (8 iters)
    {
        const uint4* Tl4 = reinterpret_cast<const uint4*>(T + (size_t)l * HSIZE);
        uint4* lds4 = reinterpret_cast<uint4*>(lds);
#pragma unroll
        for (int k = 0; k < HSIZE / 4 / BLK; ++k)
            lds4[k * BLK + t] = Tl4[k * BLK + t];
    }
    __syncthreads();

    const float r = res.v[l];
    const int base = chunk * PPB;

#pragma unroll 2
    for (int k = 0; k < PPB; k += UN * BLK) {
        int   n[UN];
        bool  ok[UN];
        float acc0[UN], acc1[UN];
        float w2v[UN], w2a_[UN];
        float wxy00[UN], wxy10[UN], wxy01[UN], wxy11[UN];
        uint32_t hx0[UN], hx1[UN], hy0[UN], hy1[UN], hz0[UN], hz1[UN];

#pragma unroll
        for (int u = 0; u < UN; ++u) {
            n[u]  = base + k + u * BLK + t;
            ok[u] = FULL || (n[u] < nPoints);
            int m = FULL ? n[u] : (ok[u] ? n[u] : 0);
            // bit-exact replication of reference fp32 grid math
            float xn0 = (x[3 * m + 0] + 1.0f) * 0.5f;
            float xn1 = (x[3 * m + 1] + 1.0f) * 0.5f;
            float xn2 = (x[3 * m + 2] + 1.0f) * 0.5f;
            float xl0 = xn0 * r, xl1 = xn1 * r, xl2 = xn2 * r;
            float fl0 = floorf(xl0), fl1 = floorf(xl1), fl2 = floorf(xl2);
            float w0 = xl0 - fl0, w1 = xl1 - fl1, w2 = xl2 - fl2;
            uint32_t i0 = (uint32_t)fl0, i1 = (uint32_t)fl1, i2 = (uint32_t)fl2;

            hx0[u] = i0;          hx1[u] = i0 + 1u;
            hy0[u] = i1 * PRIME1; hy1[u] = hy0[u] + PRIME1;   // (i1+1)*P1 mod 2^32
            hz0[u] = i2 * PRIME2; hz1[u] = hz0[u] + PRIME2;

            float w0a = 1.0f - w0, w1a = 1.0f - w1;
            w2v[u] = w2; w2a_[u] = 1.0f - w2;
            wxy00[u] = w0a * w1a; wxy10[u] = w0 * w1a;
            wxy01[u] = w0a * w1;  wxy11[u] = w0 * w1;
            acc0[u] = 0.0f; acc1[u] = 0.0f;
        }

        // 16 independent gathers (8 per point, 2 points); consume via fma_mix
#pragma unroll
        for (int c = 0; c < 8; ++c) {
#pragma unroll
            for (int u = 0; u < UN; ++u) {
                uint32_t h = ((c & 1) ? hx1[u] : hx0[u]) ^ ((c & 2) ? hy1[u] : hy0[u])
                           ^ ((c & 4) ? hz1[u] : hz0[u]);
                uint32_t pk = lds[h & (HSIZE - 1)];
                float wxy = (c & 2) ? ((c & 1) ? wxy11[u] : wxy01[u])
                                    : ((c & 1) ? wxy10[u] : wxy00[u]);
                float wc = wxy * ((c & 4) ? w2v[u] : w2a_[u]);
                fma_mix_lo(acc0[u], pk, wc);
                fma_mix_hi(acc1[u], pk, wc);
            }
        }

#pragma unroll
        for (int u = 0; u < UN; ++u) {
            if (FULL || ok[u]) {
                *reinterpret_cast<float2*>(out + (size_t)n[u] * 32 + 2 * l) =
                    make_float2(acc0[u], acc1[u]);
            }
        }
    }
}

// ---------------- Fallback: on-the-fly LoRA dequant, global gather (tiny ws) --------
__global__ void encode_fallback_k(const float* __restrict__ x, const float* __restrict__ A,
                                  const float* __restrict__ B, float* __restrict__ out,
                                  int nPoints, ResArr res) {
    int n = blockIdx.x * blockDim.x + threadIdx.x;
    if (n >= nPoints) return;
    float xn0 = (x[3 * n + 0] + 1.0f) * 0.5f;
    float xn1 = (x[3 * n + 1] + 1.0f) * 0.5f;
    float xn2 = (x[3 * n + 2] + 1.0f) * 0.5f;
    for (int l = 0; l < NLEVELS; ++l) {
        float r = res.v[l];
        float xl0 = xn0 * r, xl1 = xn1 * r, xl2 = xn2 * r;
        float fl0 = floorf(xl0), fl1 = floorf(xl1), fl2 = floorf(xl2);
        float w0 = xl0 - fl0, w1 = xl1 - fl1, w2 = xl2 - fl2;
        uint32_t i0 = (uint32_t)fl0, i1 = (uint32_t)fl1, i2 = (uint32_t)fl2;
        uint32_t hx0 = i0,          hx1 = i0 + 1u;
        uint32_t hy0 = i1 * PRIME1, hy1 = hy0 + PRIME1;
        uint32_t hz0 = i2 * PRIME2, hz1 = hz0 + PRIME2;
        float w0a = 1.0f - w0, w1a = 1.0f - w1, w2a = 1.0f - w2;
        float wxy00 = w0a * w1a, wxy10 = w0 * w1a, wxy01 = w0a * w1, wxy11 = w0 * w1;
        const float* b = B + l * 8;
        float b00 = b[0], b01 = b[1], b10 = b[2], b11 = b[3];
        float b20 = b[4], b21 = b[5], b30 = b[6], b31 = b[7];
        float acc0 = 0.0f, acc1 = 0.0f;
#pragma unroll
        for (int c = 0; c < 8; ++c) {
            uint32_t h = ((c & 1) ? hx1 : hx0) ^ ((c & 2) ? hy1 : hy0) ^ ((c & 4) ? hz1 : hz0);
            uint32_t idx = h & (HSIZE - 1);
            float4 a = *reinterpret_cast<const float4*>(A + ((size_t)l * HSIZE + idx) * RANKK);
            float fe0 = a.x * b00 + a.y * b10 + a.z * b20 + a.w * b30;
            float fe1 = a.x * b01 + a.y * b11 + a.z * b21 + a.w * b31;
            float wxy = (c & 2) ? ((c & 1) ? wxy11 : wxy01) : ((c & 1) ? wxy10 : wxy00);
            float wc = wxy * ((c & 4) ? w2 : w2a);
            acc0 = fmaf(fe0, wc, acc0);
            acc1 = fmaf(fe1, wc, acc1);
        }
        out[(size_t)n * 32 + 2 * l + 0] = acc0;
        out[(size_t)n * 32 + 2 * l + 1] = acc1;
    }
}

extern "C" void kernel_launch(void* const* d_in, const int* in_sizes, int n_in,
                              void* d_out, int out_size, void* d_ws, size_t ws_size,
                              hipStream_t stream) {
    const float* x = (const float*)d_in[0];
    const float* A = (const float*)d_in[1];
    const float* B = (const float*)d_in[2];
    float* out = (float*)d_out;
    int nPoints = in_sizes[0] / 3;

    // numpy's resolution ladder, bit-exact via host double libm:
    // b = exp((log(512)-log(16))/15); res_l = float32(floor(16 * b**l))
    ResArr ra;
    {
        double b = exp((log(512.0) - log(16.0)) / 15.0);
        for (int l = 0; l < NLEVELS; ++l)
            ra.v[l] = (float)floor(16.0 * pow(b, (double)l));
    }

    const size_t tblBytes = (size_t)NLEVELS * HSIZE * sizeof(uint32_t);   // 2 MiB

    if (ws_size >= tblBytes) {
        uint32_t* T = (uint32_t*)d_ws;
        int nb1 = (NLEVELS * HSIZE + 255) / 256;
        build_tables_k<<<nb1, 256, 0, stream>>>(A, B, T);
        int chunks = (nPoints + PPB - 1) / PPB;           // 32 for N=524288 (mult of 8)
        if (nPoints % PPB == 0) {
            encode_level_k<true><<<chunks * NLEVELS, BLK, 0, stream>>>(
                x, T, out, nPoints, chunks, ra);
        } else {
            encode_level_k<false><<<chunks * NLEVELS, BLK, 0, stream>>>(
                x, T, out, nPoints, chunks, ra);
        }
    } else {
        encode_fallback_k<<<(nPoints + 255) / 256, 256, 0, stream>>>(x, A, B, out, nPoints, ra);
    }
}